// Round 6
// baseline (545.889 us; speedup 1.0000x reference)
//
#include <hip/hip_runtime.h>
#include <math.h>

typedef __bf16 bf16_t;
typedef __bf16 bf16x8 __attribute__((ext_vector_type(8)));
typedef float f32x4 __attribute__((ext_vector_type(4)));

// async global->LDS, 16B per lane; LDS dest is wave-uniform base + lane*16
#define LDS16(g, l) __builtin_amdgcn_global_load_lds( \
    (__attribute__((address_space(1))) void*)(g),     \
    (__attribute__((address_space(3))) void*)(l), 16, 0, 0)

// ---------------------------------------------------------------------------
// Prep kernel: blocks [0,11264) fp32->bf16 flat weight cvt;
// [11264,12288) out_proj^T (32x32 tiles); [12288,20480) rmsnorm(x)*ln1 -> h1
// ---------------------------------------------------------------------------
__global__ __launch_bounds__(256) void prep_kernel(
    const float* __restrict__ qp, const float* __restrict__ kp,
    const float* __restrict__ vp, const float* __restrict__ f1,
    const float* __restrict__ f2, const float* __restrict__ op,
    const float* __restrict__ x, const float* __restrict__ ln1,
    bf16_t* __restrict__ qkvb, bf16_t* __restrict__ f1b,
    bf16_t* __restrict__ f2b, bf16_t* __restrict__ opT,
    bf16_t* __restrict__ h1)
{
    __shared__ float tile[32][33];
    __shared__ float red[4];
    int bid = blockIdx.x;
    int t = threadIdx.x;
    if (bid < 11264) {
        size_t i = ((size_t)bid * 256 + t) * 4;
        const float* src;
        bf16_t* dst;
        if (i < 3145728) {
            if (i < 1048576)      { src = qp + i;             dst = qkvb + i; }
            else if (i < 2097152) { src = kp + (i - 1048576); dst = qkvb + i; }
            else                  { src = vp + (i - 2097152); dst = qkvb + i; }
        } else if (i < 7340032) { src = f1 + (i - 3145728); dst = f1b + (i - 3145728); }
        else                    { src = f2 + (i - 7340032); dst = f2b + (i - 7340032); }
        float4 v = *(const float4*)src;
        dst[0] = (bf16_t)v.x; dst[1] = (bf16_t)v.y;
        dst[2] = (bf16_t)v.z; dst[3] = (bf16_t)v.w;
    } else if (bid < 12288) {
        int b2 = bid - 11264;
        int c0 = (b2 & 31) * 32, r0 = (b2 >> 5) * 32;
        int tx = t & 31, ty = t >> 5;  // 32 x 8
#pragma unroll
        for (int i = 0; i < 32; i += 8)
            tile[ty + i][tx] = op[(size_t)(r0 + ty + i) * 1024 + c0 + tx];
        __syncthreads();
#pragma unroll
        for (int i = 0; i < 32; i += 8)
            opT[(size_t)(c0 + ty + i) * 1024 + r0 + tx] = (bf16_t)tile[tx][ty + i];
    } else {
        int row = bid - 12288;
        float4 xv = ((const float4*)(x + (size_t)row * 1024))[t];
        float ss = xv.x * xv.x + xv.y * xv.y + xv.z * xv.z + xv.w * xv.w;
#pragma unroll
        for (int o = 32; o > 0; o >>= 1) ss += __shfl_xor(ss, o, 64);
        if ((t & 63) == 0) red[t >> 6] = ss;
        __syncthreads();
        ss = red[0] + red[1] + red[2] + red[3];
        float rinv = rsqrtf(ss * (1.0f / 1024.0f) + 1e-5f);
        float4 wv = ((const float4*)ln1)[t];
        bf16_t* hp = h1 + (size_t)row * 1024 + t * 4;
        hp[0] = (bf16_t)(xv.x * rinv * wv.x);
        hp[1] = (bf16_t)(xv.y * rinv * wv.y);
        hp[2] = (bf16_t)(xv.z * rinv * wv.z);
        hp[3] = (bf16_t)(xv.w * rinv * wv.w);
    }
}

// ---------------------------------------------------------------------------
// RMSNorm standalone (for h2): fp32 x in, bf16 h = x/rms(x)*w
// ---------------------------------------------------------------------------
__global__ __launch_bounds__(256) void rmsnorm_kernel(
    const float* __restrict__ x, const float* __restrict__ w,
    bf16_t* __restrict__ h)
{
    int row = blockIdx.x;
    int t = threadIdx.x;
    float4 xv = ((const float4*)(x + (size_t)row * 1024))[t];
    float ss = xv.x * xv.x + xv.y * xv.y + xv.z * xv.z + xv.w * xv.w;
#pragma unroll
    for (int o = 32; o > 0; o >>= 1) ss += __shfl_xor(ss, o, 64);
    __shared__ float red[4];
    if ((t & 63) == 0) red[t >> 6] = ss;
    __syncthreads();
    ss = red[0] + red[1] + red[2] + red[3];
    float rinv = rsqrtf(ss * (1.0f / 1024.0f) + 1e-5f);
    float4 wv = ((const float4*)w)[t];
    bf16_t* hp = h + (size_t)row * 1024 + t * 4;
    hp[0] = (bf16_t)(xv.x * rinv * wv.x);
    hp[1] = (bf16_t)(xv.y * rinv * wv.y);
    hp[2] = (bf16_t)(xv.z * rinv * wv.z);
    hp[3] = (bf16_t)(xv.w * rinv * wv.w);
}

// ---------------------------------------------------------------------------
// bf16 batched transpose with input row stride: out[c][r] = in[r*ldin + c]
// ---------------------------------------------------------------------------
__global__ __launch_bounds__(256) void transpose_bf16(
    const bf16_t* __restrict__ in, bf16_t* __restrict__ out,
    int rows, int ldin, long long sIn, long long sOut)
{
    __shared__ bf16_t tile[32][33];
    int b = blockIdx.z;
    const bf16_t* ip = in + (long long)b * sIn;
    bf16_t* op = out + (long long)b * sOut;
    int c0 = blockIdx.x * 32, r0 = blockIdx.y * 32;
    int tx = threadIdx.x & 31, ty = threadIdx.x >> 5;
#pragma unroll
    for (int i = 0; i < 32; i += 8)
        tile[ty + i][tx] = ip[(size_t)(r0 + ty + i) * ldin + c0 + tx];
    __syncthreads();
#pragma unroll
    for (int i = 0; i < 32; i += 8)
        op[(size_t)(c0 + ty + i) * rows + r0 + tx] = tile[tx][ty + i];
}

// ---------------------------------------------------------------------------
// Causal softmax, in place, vectorized. Row q: softmax over cols [0,q];
// writes zeros up to the next 128-boundary (all AV-gemm ever reads, due to
// its K-clamp). Cols beyond that left untouched.
// ---------------------------------------------------------------------------
__global__ __launch_bounds__(256) void causal_softmax_kernel(bf16_t* __restrict__ SP)
{
    const int S = 2048;
    int q = blockIdx.x, b = blockIdx.y;
    bf16_t* row = SP + ((size_t)b * S + q) * S;
    int t = threadIdx.x;
    int j0 = t * 8;
    int Jstore = ((q >> 7) + 1) << 7;

    float v[8];
    if (j0 + 7 <= q) {
        bf16x8 xv = *(const bf16x8*)(row + j0);
#pragma unroll
        for (int i = 0; i < 8; i++) v[i] = (float)xv[i];
    } else if (j0 <= q) {
#pragma unroll
        for (int i = 0; i < 8; i++)
            v[i] = (j0 + i <= q) ? (float)row[j0 + i] : -1e30f;
    } else {
#pragma unroll
        for (int i = 0; i < 8; i++) v[i] = -1e30f;
    }

    float mx = v[0];
#pragma unroll
    for (int i = 1; i < 8; i++) mx = fmaxf(mx, v[i]);
#pragma unroll
    for (int o = 32; o > 0; o >>= 1) mx = fmaxf(mx, __shfl_xor(mx, o, 64));
    __shared__ float sm[4], ssum[4];
    if ((t & 63) == 0) sm[t >> 6] = mx;
    __syncthreads();
    mx = fmaxf(fmaxf(sm[0], sm[1]), fmaxf(sm[2], sm[3]));

    float e[8];
    float sum = 0.f;
#pragma unroll
    for (int i = 0; i < 8; i++) {
        e[i] = (v[i] > -1e29f) ? expf(v[i] - mx) : 0.f;
        sum += e[i];
    }
#pragma unroll
    for (int o = 32; o > 0; o >>= 1) sum += __shfl_xor(sum, o, 64);
    if ((t & 63) == 0) ssum[t >> 6] = sum;
    __syncthreads();
    sum = ssum[0] + ssum[1] + ssum[2] + ssum[3];
    float r = 1.0f / sum;

    if (j0 < Jstore) {
        bf16x8 ov;
#pragma unroll
        for (int i = 0; i < 8; i++) ov[i] = (bf16_t)(e[i] * r);
        *(bf16x8*)(row + j0) = ov;
    }
}

// ---------------------------------------------------------------------------
// MFMA GEMM: C[M,N] = A * B^T, A [M][lda] row-major (K used), B [N][ldb]
// row-major (K used), fp32 accum. 128x128 tile, BK=64, 4 waves (2x2),
// 64x64/wave, 16x16x32 bf16 MFMA, 2 K-halves per LDS tile.
//
// LDS tile [128 rows][8 slots x 8 bf16] (16 KB each), XOR-swizzled:
// k-group g of row r lives in slot s = g ^ (r&7) -> ds_read_b128 2-way (free).
//
// Block decode:
//   TRI=1: blockIdx.x enumerates lower-triangular tiles (i -> bm,bn via
//          triangular root) — zero dead blocks, even XCD spread (scores).
//   TRI=0: N-partitioned XCD decode: xcd = id&7 owns bn chunk of Nt/8 tiles
//          -> per-XCD B footprint Nt/8*256KiB (L2-resident for weights);
//          bm = p/chunk spreads M (and CKLOOP work) evenly across XCDs.
// EPI 0: bf16 C=v*scale | 1: bf16 C=gelu(v) | 2: fp32 C=v+R (C may alias R
// per-element; no restrict, load precedes store).
// CKLOOP: Keff=min(K,(bm+1)*128) (causal attn*V; masked probs are 0).
// ---------------------------------------------------------------------------
template <int EPI, bool TRI, bool CKLOOP>
__global__ __launch_bounds__(256) void gemm_bt(
    const bf16_t* __restrict__ A, int lda, const bf16_t* __restrict__ B, int ldb,
    void* Cv, int ldc, const float* R,
    int K, int Nt, long long sA, long long sB, long long sC, float scale)
{
    int bz = blockIdx.z;
    int bm, bn;
    if (TRI) {
        int i = blockIdx.x;
        bm = (int)((sqrtf(8.0f * i + 1.0f) - 1.0f) * 0.5f);
        while ((bm + 1) * (bm + 2) / 2 <= i) bm++;
        while (bm * (bm + 1) / 2 > i) bm--;
        bn = i - bm * (bm + 1) / 2;
    } else {
        int id = blockIdx.x;
        int xcd = id & 7, p = id >> 3;
        int cn = Nt >> 3;
        bn = xcd * cn + p % cn;
        bm = p / cn;
    }

    __shared__ __align__(16) bf16_t At[128 * 64];
    __shared__ __align__(16) bf16_t Bt[128 * 64];
    int t = threadIdx.x;
    int w = t >> 6, l = t & 63;
    int wm = w >> 1, wn = w & 1;
    int lane_m = l & 15, quad = l >> 4;

    const bf16_t* Ag = A + (long long)bz * sA + (size_t)(bm * 128) * lda;
    const bf16_t* Bg = B + (long long)bz * sB + (size_t)(bn * 128) * ldb;

    int Keff = K;
    if (CKLOOP) {
        int kk = (bm + 1) * 128;
        if (kk < K) Keff = kk;
    }

    f32x4 acc[4][4] = {};

    // staging: thread (w,l) handles chunks cl = w*64 + 256*j + l, j=0..3.
    // cl -> LDS row r=cl>>3, slot s=cl&7; source k-group g = s ^ (r&7).
    int rb = w * 8 + (l >> 3);
    int g0 = ((l & 7) ^ ((l >> 3) & 7)) * 8;
    const bf16_t* a0[4];
    const bf16_t* b0[4];
#pragma unroll
    for (int j = 0; j < 4; j++) {
        size_t ro = (size_t)(rb + 32 * j);
        a0[j] = Ag + ro * lda + g0;
        b0[j] = Bg + ro * ldb + g0;
    }

    // ds_read slots: row = wm*64+mi*16+lane_m -> row&7 = lane_m&7
    int s0 = (quad ^ (lane_m & 7)) * 8;        // k-half 0: g = quad
    int s1 = ((4 + quad) ^ (lane_m & 7)) * 8;  // k-half 1: g = 4+quad

    for (int kt = 0; kt < Keff; kt += 64) {
        __syncthreads();
#pragma unroll
        for (int j = 0; j < 4; j++) {
            LDS16(a0[j] + kt, At + (size_t)w * 512 + j * 2048);
            LDS16(b0[j] + kt, Bt + (size_t)w * 512 + j * 2048);
        }
        __syncthreads();

#pragma unroll
        for (int h = 0; h < 2; h++) {
            int sh = h ? s1 : s0;
            bf16x8 af[4], bfr[4];
#pragma unroll
            for (int mi = 0; mi < 4; mi++)
                af[mi] = *(const bf16x8*)(At + (wm * 64 + mi * 16 + lane_m) * 64 + sh);
#pragma unroll
            for (int ni = 0; ni < 4; ni++)
                bfr[ni] = *(const bf16x8*)(Bt + (wn * 64 + ni * 16 + lane_m) * 64 + sh);
#pragma unroll
            for (int mi = 0; mi < 4; mi++)
#pragma unroll
                for (int ni = 0; ni < 4; ni++)
                    acc[mi][ni] = __builtin_amdgcn_mfma_f32_16x16x32_bf16(
                        af[mi], bfr[ni], acc[mi][ni], 0, 0, 0);
        }
    }

    long long cbase = (long long)bz * sC;
#pragma unroll
    for (int mi = 0; mi < 4; mi++) {
#pragma unroll
        for (int r = 0; r < 4; r++) {
            int row = bm * 128 + wm * 64 + mi * 16 + quad * 4 + r;
#pragma unroll
            for (int ni = 0; ni < 4; ni++) {
                int col = bn * 128 + wn * 64 + ni * 16 + lane_m;
                float v = acc[mi][ni][r];
                size_t idx = (size_t)(cbase + (long long)row * ldc + col);
                if (EPI == 0) {
                    ((bf16_t*)Cv)[idx] = (bf16_t)(v * scale);
                } else if (EPI == 1) {
                    float g = 0.5f * v * (1.0f + erff(v * 0.70710678118654752f));
                    ((bf16_t*)Cv)[idx] = (bf16_t)g;
                } else {
                    float rv = R[(size_t)row * ldc + col];
                    ((float*)Cv)[idx] = v + rv;
                }
            }
        }
    }
}

// ---------------------------------------------------------------------------
// Launch. fp32 I/O, bf16 internals.
// ws layout (MiB): [0,6) qkvb | [6,8) opT | [8,16) f1b | [16,24) f2b
//   [24,40) h1 -> VT -> h2 (disjoint lifetimes)
//   [40,88) QKVb; then AV [40,56); then G [40,104) ([8192][4096] contiguous,
//   big-ws path, ws>=104 MiB) or G0 [40,72) halves (fallback)
// SP (bf16 32 MiB) lives in d_out (fp32, unused until out_proj).
// ---------------------------------------------------------------------------
extern "C" void kernel_launch(void* const* d_in, const int* in_sizes, int n_in,
                              void* d_out, int out_size, void* d_ws, size_t ws_size,
                              hipStream_t stream)
{
    (void)in_sizes; (void)n_in; (void)out_size;
    const float* x    = (const float*)d_in[0];
    const float* ln1  = (const float*)d_in[1];
    const float* ln2  = (const float*)d_in[2];
    const float* ffn1 = (const float*)d_in[3];
    const float* ffn2 = (const float*)d_in[4];
    const float* kp   = (const float*)d_in[5];
    const float* qp   = (const float*)d_in[6];
    const float* vp   = (const float*)d_in[7];
    const float* op   = (const float*)d_in[8];
    float* out = (float*)d_out;

    const size_t MiB = 1048576;
    char* ws = (char*)d_ws;
    bf16_t* qkvb = (bf16_t*)(ws + 0 * MiB);
    bf16_t* opT  = (bf16_t*)(ws + 6 * MiB);
    bf16_t* f1b  = (bf16_t*)(ws + 8 * MiB);
    bf16_t* f2b  = (bf16_t*)(ws + 16 * MiB);
    bf16_t* h1   = (bf16_t*)(ws + 24 * MiB);
    bf16_t* VT   = (bf16_t*)(ws + 24 * MiB);  // h1 dead after QKV gemm
    bf16_t* h2   = (bf16_t*)(ws + 24 * MiB);  // VT dead after AV gemm
    bf16_t* QKVb = (bf16_t*)(ws + 40 * MiB);  // [8192][3072]
    bf16_t* AV   = (bf16_t*)(ws + 40 * MiB);  // QKVb dead after V^T
    bf16_t* G    = (bf16_t*)(ws + 40 * MiB);  // AV dead after out_proj
    bf16_t* SP   = (bf16_t*)d_out;
    bool bigws = ws_size >= 104 * MiB;

    dim3 blk(256);

    // 1) prep: weight cvt + out_proj^T + rmsnorm1
    prep_kernel<<<dim3(20480), blk, 0, stream>>>(
        qp, kp, vp, ffn1, ffn2, op, x, ln1, qkvb, f1b, f2b, opT, h1);

    // 2) fused QKV: [8192,1024] x [3072,1024]^T -> QKVb  (Nt=24, Mt=64)
    gemm_bt<0, false, false><<<dim3(1536), blk, 0, stream>>>(
        h1, 1024, qkvb, 1024, QKVb, 3072, nullptr, 1024, 24, 0, 0, 0, 1.0f);

    // 3) scores = Q K^T / 32, triangular tile enumeration -> SP (in d_out)
    gemm_bt<0, true, false><<<dim3(136, 1, 4), blk, 0, stream>>>(
        QKVb, 3072, QKVb + 1024, 3072, SP, 2048, nullptr, 1024, 16,
        (long long)2048 * 3072, (long long)2048 * 3072, (long long)2048 * 2048,
        1.0f / 32.0f);

    // 4) V -> V^T per batch (V = QKVb cols [2048,3072); VT into h1 slot)
    transpose_bf16<<<dim3(32, 64, 4), blk, 0, stream>>>(
        QKVb + 2048, VT, 2048, 3072,
        (long long)2048 * 3072, (long long)1024 * 2048);

    // 5) causal softmax in place (vectorized, causal-skip)
    causal_softmax_kernel<<<dim3(2048, 4), blk, 0, stream>>>(SP);

    // 6) AV = P @ V (B = V^T [1024][2048], causal K clamp; Nt=8 -> bn=xcd,
    //    bm=p: heavy/light K-clamp tiles mixed evenly per XCD)
    gemm_bt<0, false, true><<<dim3(128, 1, 4), blk, 0, stream>>>(
        SP, 2048, VT, 2048, AV, 1024, nullptr, 2048, 8,
        (long long)2048 * 2048, (long long)1024 * 2048, (long long)2048 * 1024,
        1.0f);

    // 7) out = x + AV @ out_proj^T  (fp32 into d_out; SP dead)
    gemm_bt<2, false, false><<<dim3(512), blk, 0, stream>>>(
        AV, 1024, opT, 1024, out, 1024, x, 1024, 8, 0, 0, 0, 1.0f);

    // 8) h2 = rmsnorm(x) * ln2
    rmsnorm_kernel<<<dim3(8192), blk, 0, stream>>>(x, ln2, h2);

    if (bigws) {
        // 9) G = gelu(h2 @ ffn1^T), single Nt=32 dispatch, contiguous G
        gemm_bt<1, false, false><<<dim3(2048), blk, 0, stream>>>(
            h2, 1024, f1b, 1024, G, 4096, nullptr, 1024, 32, 0, 0, 0, 1.0f);
        // 10) out += G @ ffn2^T, plain K=4096 GEMM (Nt=8: B L2-resident/XCD)
        gemm_bt<2, false, false><<<dim3(512), blk, 0, stream>>>(
            G, 4096, f2b, 4096, out, 1024, out, 4096, 8, 0, 0, 0, 1.0f);
    } else {
        for (int half = 0; half < 2; half++) {
            gemm_bt<1, false, false><<<dim3(1024), blk, 0, stream>>>(
                h2, 1024, f1b + (size_t)half * 2048 * 1024, 1024, G, 2048,
                nullptr, 1024, 16, 0, 0, 0, 1.0f);
            gemm_bt<2, false, false><<<dim3(512), blk, 0, stream>>>(
                G, 2048, f2b + half * 2048, 4096, out, 1024, out,
                2048, 8, 0, 0, 0, 1.0f);
        }
    }
}